// Round 3
// baseline (11992.135 us; speedup 1.0000x reference)
//
#include <hip/hip_runtime.h>

// JBF block, LDS-free: each lane owns 4 consecutive voxels, so its record
// span is 4*500B = 2000B, 16B-aligned -> direct aligned float4 loads, no
// LDS transpose needed. 2048 blocks x 64 threads (1 wave), 8 waves/CU,
// each wave keeps ~8 outstanding 1KB float4 wave-loads -> latency hidden
// by MLP+TLP instead of LDS staging phases.
//
// Record R (0..3) within the lane's span starts at float 125*R; since
// 125*R mod 4 == R, float f = 125R+e maps to float4 (125R+e)>>2, comp
// (R+e)&3 -- all compile-time after unrolling (template<int R>).

#define REC 125

__device__ __forceinline__ void acc_elem(int z, int rr, int cc, float v,
                                         const float* __restrict__ wt,
                                         float* __restrict__ acc) {
#pragma unroll
    for (int i = 0; i < 3; ++i) {
        const int a = z - i; if (a < 0 || a > 2) continue;
#pragma unroll
        for (int j = 0; j < 3; ++j) {
            const int b = rr - j; if (b < 0 || b > 2) continue;
#pragma unroll
            for (int l = 0; l < 3; ++l) {
                const int c2 = cc - l; if (c2 < 0 || c2 > 2) continue;
                acc[(i * 3 + j) * 3 + l] =
                    fmaf(v, wt[(a * 3 + b) * 3 + c2], acc[(i * 3 + j) * 3 + l]);
            }
        }
    }
}

// conv 5x5x5 -> 27 outputs for record R of this lane's 4-record span.
// s4 = lane's 16B-aligned base. Loads 32 float4 in 4 groups of 8 with
// one-group prefetch; p[] is fully constant-indexed -> stays in VGPRs.
template <int R>
__device__ __forceinline__ void conv_record(const float4* __restrict__ s4,
                                            const float* __restrict__ wt,
                                            float* __restrict__ acc) {
    constexpr int K0 = (125 * R) >> 2;
    float p[128];
#pragma unroll
    for (int k = 0; k < 8; ++k) {            // group 0
        const float4 t = s4[K0 + k];
        p[4 * k + 0] = t.x; p[4 * k + 1] = t.y;
        p[4 * k + 2] = t.z; p[4 * k + 3] = t.w;
    }
#pragma unroll
    for (int g = 0; g < 4; ++g) {
        if (g + 1 < 4) {                     // prefetch next group
#pragma unroll
            for (int k = 0; k < 8; ++k) {
                const float4 t = s4[K0 + 8 * (g + 1) + k];
                p[32 * (g + 1) + 4 * k + 0] = t.x;
                p[32 * (g + 1) + 4 * k + 1] = t.y;
                p[32 * (g + 1) + 4 * k + 2] = t.z;
                p[32 * (g + 1) + 4 * k + 3] = t.w;
            }
        }
        // consume elements whose float (R+e) falls in group g's 32 floats
#pragma unroll
        for (int e = 0; e < 125; ++e) {
            if (R + e >= 32 * g && R + e < 32 * g + 32) {
                const int z = e / 25, rr = (e % 25) / 5, cc = e % 5;
                acc_elem(z, rr, cc, p[R + e], wt, acc);
            }
        }
    }
}

template <int R>
__device__ __forceinline__ float do_voxel(const float4* __restrict__ d4,
                                          const float4* __restrict__ g4,
                                          const float* __restrict__ x,
                                          const float* __restrict__ wd,
                                          const float* __restrict__ wr,
                                          float bd, float br,
                                          int w0, int h_, int zz0) {
    float dkv[27], rkv[27];
#pragma unroll
    for (int i = 0; i < 27; ++i) { dkv[i] = 0.f; rkv[i] = 0.f; }
    conv_record<R>(d4, wd, dkv);
    conv_record<R>(g4, wr, rkv);

    const int w_ = w0 + R;
    float num = 0.f, den = 0.f;
#pragma unroll
    for (int i = 0; i < 3; ++i) {
        const int zz = zz0 + i;
#pragma unroll
        for (int j = 0; j < 3; ++j) {
            const int hh = h_ - 1 + j;
            const bool okh = (unsigned)hh < 128u;
#pragma unroll
            for (int l = 0; l < 3; ++l) {
                const int ww = w_ - 1 + l;
                const bool ok = okh && ((unsigned)ww < 128u);
                const float xv = ok ? x[((size_t)zz * 128 + hh) * 128 + ww] : 0.f;
                const float wv = fmaxf(dkv[(i * 3 + j) * 3 + l] + bd, 0.f) *
                                 fmaxf(rkv[(i * 3 + j) * 3 + l] + br, 0.f) + 1e-10f;
                den += wv;
                num = fmaf(wv, xv, num);
            }
        }
    }
    return num / den;
}

__global__ __launch_bounds__(64, 3) void jbf_kernel(
    const float* __restrict__ x,      // [2,1,18,128,128]
    const float* __restrict__ dom,    // [M,125]
    const float* __restrict__ gui,    // [M,125]
    const float* __restrict__ dom_w,  // [27]
    const float* __restrict__ dom_b,  // [1]
    const float* __restrict__ rng_w,  // [27]
    const float* __restrict__ rng_b,  // [1]
    float* __restrict__ out)          // [M]
{
    const int gid = blockIdx.x * 64 + threadIdx.x;  // lane over M/4
    const int V   = gid * 4;                        // first owned voxel

    // wave-uniform weights -> scalar loads/SGPRs
    float wd[27], wr[27];
#pragma unroll
    for (int i = 0; i < 27; ++i) { wd[i] = dom_w[i]; wr[i] = rng_w[i]; }
    const float bd = dom_b[0], br = rng_b[0];

    const float4* d4 = (const float4*)(dom + (size_t)V * REC);  // 2000B-aligned
    const float4* g4 = (const float4*)(gui + (size_t)V * REC);

    // voxel index decode: m = ((b*16+dz)*128+h)*128+w ; V multiple of 4 so
    // h_, dz, b_ identical for all 4 owned voxels, w varies by +R (no carry).
    const int w0  = V & 127;
    const int h_  = (V >> 7) & 127;
    const int dz  = (V >> 14) & 15;
    const int b_  = V >> 18;
    const int zz0 = b_ * 18 + dz;

    float res[4];
    res[0] = do_voxel<0>(d4, g4, x, wd, wr, bd, br, w0, h_, zz0);
    __builtin_amdgcn_sched_barrier(0);   // stop cross-record load hoisting
    res[1] = do_voxel<1>(d4, g4, x, wd, wr, bd, br, w0, h_, zz0);
    __builtin_amdgcn_sched_barrier(0);
    res[2] = do_voxel<2>(d4, g4, x, wd, wr, bd, br, w0, h_, zz0);
    __builtin_amdgcn_sched_barrier(0);
    res[3] = do_voxel<3>(d4, g4, x, wd, wr, bd, br, w0, h_, zz0);

    // coalesced 16B/lane store: out + 4*gid floats = 16B*gid
    *(float4*)(out + V) = make_float4(res[0], res[1], res[2], res[3]);
}

extern "C" void kernel_launch(void* const* d_in, const int* in_sizes, int n_in,
                              void* d_out, int out_size, void* d_ws, size_t ws_size,
                              hipStream_t stream) {
    const float* x     = (const float*)d_in[0];
    const float* dom   = (const float*)d_in[1];
    const float* gui   = (const float*)d_in[2];
    const float* dom_w = (const float*)d_in[3];
    const float* dom_b = (const float*)d_in[4];
    const float* rng_w = (const float*)d_in[5];
    const float* rng_b = (const float*)d_in[6];
    float* outp = (float*)d_out;

    const int M = in_sizes[1] / REC;       // 524288
    const int grid = M / (4 * 64);         // 2048 blocks (8/CU), 1 wave each
    jbf_kernel<<<grid, 64, 0, stream>>>(x, dom, gui, dom_w, dom_b,
                                        rng_w, rng_b, outp);
}